// Round 17
// baseline (32.474 us; speedup 1.0000x reference)
//
#include <hip/hip_runtime.h>

// LBP forward: out[n,f,h,w] = sum_p 2^p * sigmoid((nb - ctr)/0.1)
//   c  = projection_map[f,p]; ky,kx = kernels[f,p,:] in {0,1,2}
//   nb  = xpad[n,c,h+ky-1,w+kx-1]  (zero pad of 1), ctr = x[n,c,h,w]
// N=32 D=64 H=56 W=56 F=128 P=4
//
// Round-17: occupancy experiment. r8-r16 varied LDS instrs/bytes/math 2x+
// with total pinned at 26.5-30us -> compute phase is latency-bound at the
// one constant: 16 waves/CU (1 block/CU, big tile). This round: fp32 tile
// [64ch][4 trow][64 col] = EXACTLY 64KB -> 2 blocks/CU = 32 waves/CU
// (8/SIMD, 2x latency coverage). ROWS=2 per block, 28 strips x 32 n = 896
// blocks, grid.x = n (XCD pin: halo re-reads L2-local).
// __launch_bounds__(1024,8) caps VGPR<=64; table prefetch rotation dropped
// (s_load per f-iter, hidden by 8 waves/SIMD; also removes the r16 uninit-
// prefetch UB suspected in the post-timing divergence).
// Center taps (ky==1&&kx==1) contribute exactly wt/2 -> folded into INI,
// skipped entirely (~11% fewer reads+math).
// Sigmoid: 7-VALU min-of-tangent-lines, zero trans (r9/r11-proven, 0.1875).

#define NN 32
#define DD 64
#define HH 56
#define WW 56
#define FF 128
#define PP 4

#define ROWS 2            // output rows per block
#define TRW  4            // tile rows incl. halo
#define TC   64           // padded cols: data at 4..59, zero pads at 3, 60
#define COL0 4
#define CHS  (TRW * TC)   // 256 floats per channel
#define TILE_FLOATS (DD * CHS)   // 16384 floats = 65536 B (2 blocks/CU)
#define NSTRIP 28         // 28 * 2 = 56 rows
#define NTHREADS 1024
#define NWAVES 16
#define FITER (FF / NWAVES)      // 8 f per wave
#define NITEMS (DD * TRW * 14)   // 3584 staging float4 items

__global__ __launch_bounds__(NTHREADS, 8) void lbp_kernel(
    const float* __restrict__ x,    // (N,D,H,W)
    const int*   __restrict__ kern, // (F,P,2)
    const int*   __restrict__ proj, // (F,P)
    float*       __restrict__ out)  // (N,F,H,W)
{
    __shared__ float tile[TILE_FLOATS];   // 65536 B

    const int tid   = threadIdx.x;
    const int n     = blockIdx.x;         // fastest -> linear id % 8 = n % 8
    const int strip = blockIdx.y;         // 0..27
    const int h0    = strip * ROWS;

    const float* xn = x + (size_t)n * (DD * HH * WW);

    // ---- stage: 3584 float4 items, issue all loads up front ----
    float4 rv[4];
    int    lo[4];
#pragma unroll
    for (int s = 0; s < 4; ++s) {
        const int item = tid + s * NTHREADS;
        rv[s] = make_float4(0.f, 0.f, 0.f, 0.f);
        lo[s] = -1;
        if (item < NITEMS) {                    // only s==3 is partial
            const int ch  = item / (TRW * 14);
            const int rem = item - ch * (TRW * 14);
            const int tr  = rem / 14;
            const int g   = rem - tr * 14;
            lo[s] = ch * CHS + tr * TC + COL0 + 4 * g;
            const int h = h0 + tr - 1;
            if ((unsigned)h < (unsigned)HH)
                rv[s] = *(const float4*)(xn + ch * (HH * WW) + h * WW + 4 * g);
        }
    }

    // ---- zero the kx-pad columns (3 and 60) while loads fly ----
    if (tid < DD * TRW * 2) {
        const int side = tid & 1;
        const int cr   = tid >> 1;              // ch*TRW + tr
        tile[cr * TC + (side ? 60 : 3)] = 0.f;
    }

    // ---- land the tile ----
#pragma unroll
    for (int s = 0; s < 4; ++s)
        if (lo[s] >= 0) *(float4*)(tile + lo[s]) = rv[s];
    __syncthreads();

    // ---- compute: wave = f-group, lane = column, 2 rows per lane ----
    const int wid  = __builtin_amdgcn_readfirstlane(tid >> 6);  // 0..15
    const int lane = tid & 63;
    const int w    = lane < WW ? lane : WW - 1;   // clamp idle lanes
    const bool act = lane < WW;
    const int cb   = TC + COL0 + w;               // ctr addr of output row 0

#pragma unroll
    for (int k = 0; k < FITER; ++k) {
        const int f = wid + k * NWAVES;           // wave-uniform

        // tables: scalar loads per iteration (L1-scalar-cached)
        const int4 pj = *(const int4*)(proj + f * PP);
        const int4 ka = *(const int4*)(kern + f * (PP * 2));
        const int4 kb = *(const int4*)(kern + f * (PP * 2) + 4);
        const int cc[4]  = {pj.x, pj.y, pj.z, pj.w};
        const int kyv[4] = {ka.x, ka.z, kb.x, kb.z};
        const int kxv[4] = {ka.y, ka.w, kb.y, kb.w};

        float acc0 = 7.5f, acc1 = 7.5f;           // sum wt*0.5 (all taps)

#pragma unroll
        for (int p = 0; p < PP; ++p) {
            const int ky = kyv[p];                // SGPR, wave-uniform
            const int kx = kxv[p];
            if (!(ky == 1 && kx == 1)) {          // center tap exact in INI
                const int pc = cc[p] * CHS + cb;                    // rows 1,2
                const int pn = cc[p] * CHS + ky * TC + COL0 + (w + kx - 1);
                const float c0 = tile[pc];
                const float c1 = tile[pc + TC];
                const float n0 = tile[pn];
                const float n1 = tile[pn + TC];
                const float wt = (float)(1 << p);

                const float d0  = n0 - c0;
                const float ad0 = __builtin_fabsf(d0);
                const float a00 = fmaf(2.5f,     ad0, -0.0078f);
                const float a01 = fmaf(1.49146f, ad0,  0.08455f);
                const float a02 = fmaf(0.45177f, ad0,  0.30774f);
                const float am0 = fminf(fminf(fminf(a00, a01), a02), 0.49140f);
                acc0 = fmaf(wt, __builtin_copysignf(am0, d0), acc0);

                const float d1  = n1 - c1;
                const float ad1 = __builtin_fabsf(d1);
                const float a10 = fmaf(2.5f,     ad1, -0.0078f);
                const float a11 = fmaf(1.49146f, ad1,  0.08455f);
                const float a12 = fmaf(0.45177f, ad1,  0.30774f);
                const float am1 = fminf(fminf(fminf(a10, a11), a12), 0.49140f);
                acc1 = fmaf(wt, __builtin_copysignf(am1, d1), acc1);
            }
        }

        if (act) {
            float* op = out + ((size_t)n * FF + f) * (HH * WW)
                            + (size_t)h0 * WW + w;
            op[0]  = acc0;
            op[WW] = acc1;
        }
    }
}

extern "C" void kernel_launch(void* const* d_in, const int* in_sizes, int n_in,
                              void* d_out, int out_size, void* d_ws, size_t ws_size,
                              hipStream_t stream) {
    const float* x    = (const float*)d_in[0];
    const int*   kern = (const int*)d_in[1];
    const int*   proj = (const int*)d_in[2];
    float*       out  = (float*)d_out;

    dim3 grid(NN, NSTRIP);   // x = n (XCD pin: id%8 = n%8), y = strip
    dim3 block(NTHREADS);
    lbp_kernel<<<grid, block, 0, stream>>>(x, kern, proj, out);
}

// Round 18
// 26.543 us; speedup vs baseline: 1.2234x; 1.2234x over previous
//
#include <hip/hip_runtime.h>

// LBP forward: out[n,f,h,w] = sum_p 2^p * sigmoid((nb - ctr)/0.1)
//   c  = projection_map[f,p]; ky,kx = kernels[f,p,:] in {0,1,2}
//   nb  = xpad[n,c,h+ky-1,w+kx-1]  (zero pad of 1), ctr = x[n,c,h,w]
// N=32 D=64 H=56 W=56 F=128 P=4
//
// Round-18 = round-11 (best: 26.6us, deterministic) + two byte-level cuts.
// Ledger r8-r17: trans/LDS-instrs/LDS-bytes/VALU/occupancy all varied >=2x,
// total pinned 26.5-33 -> family is memory-system bound (~83MB mixed R+W at
// ~4.5-5 TB/s effective) + ~5us exposed stage. Only bytes & exposure remain:
//  (a) center-tap skip: ky==kx==1 taps (1/9 of 512) contribute exactly wt/2
//      -> folded into acc init (7.5), their LDS reads AND math skipped.
//  (b) n-major grid: grid.x = n -> linear id%8 = n%8 pins all 8 strips of an
//      image to one XCD; the 2-halo-row overlap between adjacent strips
//      becomes cross-block L2 hits (fetch 33 -> ~29MB).
// Everything else identical to r11: ROWS=7 one-shot 147KB fp32 tile, bulk
// clustered reads per f-iter (one lgkmcnt join), 7-VALU trans-free sigmoid
// (absmax 0.1875 < 0.3), wave-uniform f via s_load tables w/ one-ahead
// prefetch, lane = column (stride-1, conflict-free).

#define NN 32
#define DD 64
#define HH 56
#define WW 56
#define FF 128
#define PP 4

#define ROWS 7          // output rows per block
#define TR   (ROWS + 2) // 9 tile rows incl. halo
#define TC   64         // padded cols (interior 4..59, zero pads at 3 and 60)
#define COL0 4
#define CHS  (TR * TC)  // 576 floats per channel
#define TILE_FLOATS (DD * CHS)  // 36864 floats = 147456 B
#define NTHREADS 1024
#define NWAVES 16
#define FITER (FF / NWAVES)       // 8 f per wave
#define ITEMS (DD * TR * 14)      // 8064 float4 staging items
#define NSTRIP (HH / ROWS)        // 8

__global__ __launch_bounds__(NTHREADS, 4) void lbp_kernel(
    const float* __restrict__ x,    // (N,D,H,W)
    const int*   __restrict__ kern, // (F,P,2)
    const int*   __restrict__ proj, // (F,P)
    float*       __restrict__ out)  // (N,F,H,W)
{
    __shared__ float tile[TILE_FLOATS];  // 147456 B, 1 block/CU

    const int tid = threadIdx.x;
    const int n   = blockIdx.x;          // n-major: id%8 = n%8 -> XCD pin
    const int h0  = blockIdx.y * ROWS;   // 0,7,...,49

    const float* xn = x + (size_t)n * (DD * HH * WW);

    // ---- stage: 8064 float4 items, 8/thread; all loads issued up front ----
    float4 rv[8];
    int    lo[8];
#pragma unroll
    for (int it = 0; it < 8; ++it) {
        const int item = tid + it * NTHREADS;
        rv[it] = make_float4(0.f, 0.f, 0.f, 0.f);
        lo[it] = -1;
        if (item < ITEMS) {                       // only it==7 is partial
            const int ch  = item / (TR * 14);
            const int rem = item - ch * (TR * 14);
            const int tr  = rem / 14;
            const int v   = rem - tr * 14;
            lo[it] = ch * CHS + tr * TC + COL0 + 4 * v;
            const int h = h0 + tr - 1;
            if ((unsigned)h < (unsigned)HH)
                rv[it] = *(const float4*)(xn + ch * (HH * WW) + h * WW + 4 * v);
        }
    }

    // ---- zero the kx-pad columns (3 and 60) while loads fly ----
    for (int i = tid; i < DD * TR * 2; i += NTHREADS) {
        const int ch   = i / (TR * 2);
        const int rr   = (i >> 1) % TR;
        const int side = i & 1;
        tile[ch * CHS + rr * TC + 3 + side * 57] = 0.f;
    }

    // ---- land the tile ----
#pragma unroll
    for (int it = 0; it < 8; ++it)
        if (lo[it] >= 0) *(float4*)(tile + lo[it]) = rv[it];
    __syncthreads();

    // ---- compute: wave = f-group, lane = column, 7 rows per lane ----
    const int wid  = __builtin_amdgcn_readfirstlane(tid >> 6);  // 0..15
    const int lane = tid & 63;
    const int w    = lane < WW ? lane : WW - 1;  // clamp idle lanes
    const bool act = lane < WW;
    const int cb   = TC + COL0 + w;              // ctr addr of output row 0

    int f = wid;
    int4 pj = *(const int4*)(proj + f * PP);
    int4 ka = *(const int4*)(kern + f * (PP * 2));
    int4 kb = *(const int4*)(kern + f * (PP * 2) + 4);

#pragma unroll
    for (int k = 0; k < FITER; ++k) {
        const int fn = f + NWAVES;
        int4 pjn, kan, kbn;
        if (fn < FF) {                 // one-ahead table prefetch (s_load)
            pjn = *(const int4*)(proj + fn * PP);
            kan = *(const int4*)(kern + fn * (PP * 2));
            kbn = *(const int4*)(kern + fn * (PP * 2) + 4);
        }
        const int cc[4]  = {pj.x, pj.y, pj.z, pj.w};
        const int kyv[4] = {ka.x, ka.z, kb.x, kb.z};
        const int kxv[4] = {ka.y, ka.w, kb.y, kb.w};

        // ---- bulk reads: skip center taps; static indexing, one join ----
        float cv[PP][ROWS], nv[PP][ROWS];
#pragma unroll
        for (int p = 0; p < PP; ++p) {
            const int ky = kyv[p];                    // wave-uniform
            const int kx = kxv[p];
            if (!(ky == 1 && kx == 1)) {              // center tap exact in INI
                const int pc = cc[p] * CHS + cb;                      // ctr row 0
                const int pn = pc + (ky - 1) * TC + (kx - 1);         // neighbor
#pragma unroll
                for (int r = 0; r < ROWS; ++r) {
                    cv[p][r] = tile[pc + r * TC];
                    nv[p][r] = tile[pn + r * TC];
                }
            }
        }

        // ---- straight-line trans-free math: 7 VALU per eval ----
        float acc[ROWS];
#pragma unroll
        for (int r = 0; r < ROWS; ++r) acc[r] = 7.5f;  // sum wt * 0.5
#pragma unroll
        for (int p = 0; p < PP; ++p) {
            if (!(kyv[p] == 1 && kxv[p] == 1)) {
                const float wt = (float)(1 << p);
#pragma unroll
                for (int r = 0; r < ROWS; ++r) {
                    const float d  = nv[p][r] - cv[p][r];
                    const float ad = __builtin_fabsf(d);              // modifier
                    const float u0 = fmaf(2.5f,     ad, -0.0078f);
                    const float u1 = fmaf(1.49146f, ad,  0.08455f);
                    const float u2 = fmaf(0.45177f, ad,  0.30774f);
                    const float um = fminf(fminf(fminf(u0, u1), u2), 0.49140f);
                    acc[r] = fmaf(wt, __builtin_copysignf(um, d), acc[r]);
                }
            }
        }

        if (act) {
            float* op = out + ((size_t)n * FF + f) * (HH * WW)
                            + (size_t)h0 * WW + w;
#pragma unroll
            for (int r = 0; r < ROWS; ++r) op[r * WW] = acc[r];
        }
        f = fn; pj = pjn; ka = kan; kb = kbn;
    }
}

extern "C" void kernel_launch(void* const* d_in, const int* in_sizes, int n_in,
                              void* d_out, int out_size, void* d_ws, size_t ws_size,
                              hipStream_t stream) {
    const float* x    = (const float*)d_in[0];
    const int*   kern = (const int*)d_in[1];
    const int*   proj = (const int*)d_in[2];
    float*       out  = (float*)d_out;

    dim3 grid(NN, NSTRIP);   // x = n (XCD pin: id%8 = n%8), y = strip
    dim3 block(NTHREADS);
    lbp_kernel<<<grid, block, 0, stream>>>(x, kern, proj, out);
}

// Round 19
// 24.345 us; speedup vs baseline: 1.3339x; 1.0903x over previous
//
#include <hip/hip_runtime.h>

// LBP forward: out[n,f,h,w] = sum_p 2^p * sigmoid((nb - ctr)/0.1)
//   c  = projection_map[f,p]; ky,kx = kernels[f,p,:] in {0,1,2}
//   nb  = xpad[n,c,h+ky-1,w+kx-1]  (zero pad of 1), ctr = x[n,c,h,w]
// N=32 D=64 H=56 W=56 F=128 P=4
//
// Round-19: compute phase is LDS-port service bound: r18 issues ~4096
// wave-LDS-instrs/CU (~45K cyc ~ 19us) + ~6us exposed stage = 26.5 observed.
// Fix: tile packed as fp16 half2 across IMAGES (n, n+16) at identical
// (ch,row,col) -> every ds_read2_b32 serves TWO images (addressing/fusion
// byte-identical to r18), math packed (v_pk_fma/min_f16). r10 empirically
// bounded fp16-tile quant at ~0 extra absmax (0.0625 == f32). Grid z splits
// f in half -> 16 pairs x 8 strips x 2 = 256 blocks = 1/CU; grid.x = pair
// pins both f-halves + all strips of a pair to one XCD (twin stage fetch
// L2-local; 2 pairs x 1.6MB = 3.2MB < 4MB L2/XCD).
// Prefetch registers explicitly initialized (r16 UB suspect removed).
// Center taps (ky==kx==1) fold to wt/2 in acc init; reads+math skipped.
// Sigmoid: 3-tangent-line min (r9/r11-proven 0.1875) in packed f16.

#define NN 32
#define DD 64
#define HH 56
#define WW 56
#define FF 128
#define PP 4

#define ROWS 7          // output rows per block
#define TR   (ROWS + 2) // 9 tile rows incl. halo
#define TC   64         // padded cols (interior 4..59, zero pads at 3 and 60)
#define COL0 4
#define CHS  (TR * TC)  // 576 dwords per channel (each dword = half2 pair)
#define TILE_DW (DD * CHS)   // 36864 dwords = 147456 B
#define NTHREADS 1024
#define NWAVES 16
#define NPAIR 16
#define NSTRIP (HH / ROWS)       // 8
#define FH 64                    // f per block (z-split)
#define FITER (FH / NWAVES)      // 4 f per wave
#define ITEMS (DD * TR * 14)     // 8064 staging items (2 float4 loads each)
#define IMGSTR (DD * HH * WW)    // floats per image

typedef _Float16 h2 __attribute__((ext_vector_type(2)));

static __device__ __forceinline__ uint32_t h2u(h2 h) {
    union { h2 h; uint32_t u; } v; v.h = h; return v.u;
}
static __device__ __forceinline__ h2 u2h(uint32_t u) {
    union { h2 h; uint32_t u; } v; v.u = u; return v.h;
}
static __device__ __forceinline__ h2 splat(float f) {
    h2 r; r.x = (_Float16)f; r.y = (_Float16)f; return r;
}
static __device__ __forceinline__ uint32_t pack2(float a, float b) {
    h2 r; r.x = (_Float16)a; r.y = (_Float16)b; return h2u(r);
}

__global__ __launch_bounds__(NTHREADS, 4) void lbp_kernel(
    const float* __restrict__ x,    // (N,D,H,W)
    const int*   __restrict__ kern, // (F,P,2)
    const int*   __restrict__ proj, // (F,P)
    float*       __restrict__ out)  // (N,F,H,W)
{
    __shared__ uint32_t tile[TILE_DW];   // 147456 B, 1 block/CU

    const int tid = threadIdx.x;
    const int pr  = blockIdx.x;          // pair: images (pr, pr+16); XCD pin
    const int h0  = blockIdx.y * ROWS;   // 0,7,...,49
    const int fh  = blockIdx.z;          // 0..1 -> f base

    const float* x0 = x + (size_t)pr * IMGSTR;
    const float* x1 = x0 + (size_t)NPAIR * IMGSTR;

    // ---- stage: 8064 items, 8/thread; 2 float4 loads each, all up front ----
    float4 av[8], bv[8];
    int    lo[8];
#pragma unroll
    for (int it = 0; it < 8; ++it) {
        const int item = tid + it * NTHREADS;
        av[it] = make_float4(0.f, 0.f, 0.f, 0.f);
        bv[it] = make_float4(0.f, 0.f, 0.f, 0.f);
        lo[it] = -1;
        if (item < ITEMS) {                       // only it==7 is partial
            const int ch  = item / (TR * 14);
            const int rem = item - ch * (TR * 14);
            const int tr  = rem / 14;
            const int v   = rem - tr * 14;
            lo[it] = ch * CHS + tr * TC + COL0 + 4 * v;
            const int h = h0 + tr - 1;
            if ((unsigned)h < (unsigned)HH) {
                const int off = ch * (HH * WW) + h * WW + 4 * v;
                av[it] = *(const float4*)(x0 + off);
                bv[it] = *(const float4*)(x1 + off);
            }
        }
    }

    // ---- zero the kx-pad columns (3 and 60) while loads fly ----
    for (int i = tid; i < DD * TR * 2; i += NTHREADS) {
        const int ch   = i / (TR * 2);
        const int rr   = (i >> 1) % TR;
        const int side = i & 1;
        tile[ch * CHS + rr * TC + 3 + side * 57] = 0u;
    }

    // ---- pack (img0 = lo half, img1 = hi half) and land b128 ----
#pragma unroll
    for (int it = 0; it < 8; ++it) {
        if (lo[it] >= 0) {
            uint4 q;
            q.x = pack2(av[it].x, bv[it].x);
            q.y = pack2(av[it].y, bv[it].y);
            q.z = pack2(av[it].z, bv[it].z);
            q.w = pack2(av[it].w, bv[it].w);
            *(uint4*)(tile + lo[it]) = q;         // 16B aligned (COL0+4v)
        }
    }
    __syncthreads();

    // ---- compute: wave = f-group, lane = column, 7 rows x 2 images ----
    const int wid  = __builtin_amdgcn_readfirstlane(tid >> 6);  // 0..15
    const int lane = tid & 63;
    const int w    = lane < WW ? lane : WW - 1;  // clamp idle lanes
    const bool act = lane < WW;
    const int cb   = TC + COL0 + w;              // ctr addr of output row 0

    const h2 K0a = splat(2.5f),     K0b = splat(-0.0078f);
    const h2 K1a = splat(1.49146f), K1b = splat(0.08455f);
    const h2 K2a = splat(0.45177f), K2b = splat(0.30774f);
    const h2 KF  = splat(0.49140f);
    const h2 INI = splat(7.5f);                  // sum wt*0.5 over all taps

    int f = fh * FH + wid;
    int4 pj = *(const int4*)(proj + f * PP);
    int4 ka = *(const int4*)(kern + f * (PP * 2));
    int4 kb = *(const int4*)(kern + f * (PP * 2) + 4);

#pragma unroll
    for (int k = 0; k < FITER; ++k) {
        const int fn = f + NWAVES;
        int4 pjn = pj, kan = ka, kbn = kb;       // initialized (no UB)
        if (k + 1 < FITER) {                     // one-ahead table prefetch
            pjn = *(const int4*)(proj + fn * PP);
            kan = *(const int4*)(kern + fn * (PP * 2));
            kbn = *(const int4*)(kern + fn * (PP * 2) + 4);
        }
        const int cc[4]  = {pj.x, pj.y, pj.z, pj.w};
        const int kyv[4] = {ka.x, ka.z, kb.x, kb.z};
        const int kxv[4] = {ka.y, ka.w, kb.y, kb.w};

        // ---- bulk packed reads: skip center taps; one lgkmcnt join ----
        uint32_t cu[PP][ROWS], nu[PP][ROWS];
#pragma unroll
        for (int p = 0; p < PP; ++p) {
            const int ky = kyv[p];               // wave-uniform
            const int kx = kxv[p];
            if (!(ky == 1 && kx == 1)) {
                const int pc = cc[p] * CHS + cb;               // ctr row 0
                const int pn = pc + (ky - 1) * TC + (kx - 1);  // neighbor
#pragma unroll
                for (int r = 0; r < ROWS; ++r) {
                    cu[p][r] = tile[pc + r * TC];
                    nu[p][r] = tile[pn + r * TC];
                }
            }
        }

        // ---- packed trans-free sigmoid: ~6 pk-ops per eval-pair ----
        h2 acc[ROWS];
#pragma unroll
        for (int r = 0; r < ROWS; ++r) acc[r] = INI;
#pragma unroll
        for (int p = 0; p < PP; ++p) {
            if (!(kyv[p] == 1 && kxv[p] == 1)) {
                const h2 wt2 = splat((float)(1 << p));
#pragma unroll
                for (int r = 0; r < ROWS; ++r) {
                    const h2 d  = u2h(nu[p][r]) - u2h(cu[p][r]);
                    const uint32_t du = h2u(d);
                    const h2 ad = u2h(du & 0x7FFF7FFFu);
                    const h2 u0 = __builtin_elementwise_fma(K0a, ad, K0b);
                    const h2 u1 = __builtin_elementwise_fma(K1a, ad, K1b);
                    const h2 u2 = __builtin_elementwise_fma(K2a, ad, K2b);
                    const h2 um = __builtin_elementwise_min(
                                      __builtin_elementwise_min(u0, u1),
                                      __builtin_elementwise_min(u2, KF));
                    const uint32_t su = (du & 0x80008000u)
                                      | (h2u(um) & 0x7FFF7FFFu);
                    acc[r] = __builtin_elementwise_fma(wt2, u2h(su), acc[r]);
                }
            }
        }

        if (act) {
            float* o0 = out + ((size_t)pr * FF + f) * (HH * WW)
                            + (size_t)h0 * WW + w;
            float* o1 = o0 + (size_t)NPAIR * FF * (HH * WW);
#pragma unroll
            for (int r = 0; r < ROWS; ++r) {
                o0[r * WW] = (float)acc[r].x;
                o1[r * WW] = (float)acc[r].y;
            }
        }
        f = fn; pj = pjn; ka = kan; kb = kbn;
    }
}

extern "C" void kernel_launch(void* const* d_in, const int* in_sizes, int n_in,
                              void* d_out, int out_size, void* d_ws, size_t ws_size,
                              hipStream_t stream) {
    const float* x    = (const float*)d_in[0];
    const int*   kern = (const int*)d_in[1];
    const int*   proj = (const int*)d_in[2];
    float*       out  = (float*)d_out;

    dim3 grid(NPAIR, NSTRIP, 2);   // x = pair (XCD pin), y = strip, z = f-half
    dim3 block(NTHREADS);
    lbp_kernel<<<grid, block, 0, stream>>>(x, kern, proj, out);
}